// Round 23
// baseline (702.662 us; speedup 1.0000x reference)
//
#include <hip/hip_runtime.h>
#include <math.h>

#define S_LEN 1024
#define BATCH 2
#define HIDN  2048
#define NHEAD 16
#define KVHN  4
#define HDIM  128
#define FFND  4096
#define NEXP  8
#define CAPC  512
#define TTOK  2048
#define QKVSZ 3072
#define GRP   768

#define BM  128
#define BKS 32   // K-step for gemm_x3s
#define BKM 32   // K-step for gemm_moeF (R22: 64->32, halves LDS -> 5 blocks/CU)
#define LDT 40   // LDS row stride for attention P tiles

typedef float           f32x4 __attribute__((ext_vector_type(4)));
typedef __bf16          bf16x8 __attribute__((ext_vector_type(8)));
typedef unsigned short  u16x8 __attribute__((ext_vector_type(8)));
typedef unsigned short  u16x4 __attribute__((ext_vector_type(4)));

static __device__ __forceinline__ unsigned short f2bf(float f) {
  unsigned int u = __builtin_bit_cast(unsigned int, f);
  u += 0x7FFFu + ((u >> 16) & 1u);          // RTNE
  return (unsigned short)(u >> 16);
}
static __device__ __forceinline__ float bf2f(unsigned short h) {
  unsigned int u = ((unsigned int)h) << 16;
  return __builtin_bit_cast(float, u);
}
// one-instruction packed f32x2 -> bf16x2 (RTNE, matches f2bf)
static __device__ __forceinline__ unsigned int cvt_pk_bf16(float lo, float hi) {
  unsigned int r;
  asm("v_cvt_pk_bf16_f32 %0, %1, %2" : "=v"(r) : "v"(lo), "v"(hi));
  return r;
}
static __device__ __forceinline__ bf16x8 ldbf8(const unsigned short* p) {
  return __builtin_bit_cast(bf16x8, *(const u16x8*)p);
}
static __device__ __forceinline__ f32x4 mfma16(bf16x8 a, bf16x8 b, f32x4 c) {
  return __builtin_amdgcn_mfma_f32_16x16x32_bf16(a, b, c, 0, 0, 0);
}
// async global->LDS, 16B per lane; dest is wave-uniform base + lane*16
static __device__ __forceinline__ void gl_lds16(const unsigned short* g, unsigned short* l) {
  __builtin_amdgcn_global_load_lds(
      (const __attribute__((address_space(1))) unsigned int*)g,
      (__attribute__((address_space(3))) unsigned int*)l, 16, 0, 0);
}

// ---------------- LayerNorm (exact two-pass fp32), emits bf16 hi (+optional lo, +optional f32)
__global__ __launch_bounds__(256) void ln_kernel(
    const float* __restrict__ X, const float* __restrict__ W, const float* __restrict__ Bi,
    unsigned short* __restrict__ Yh, unsigned short* __restrict__ Yl, float* __restrict__ Yf) {
  __shared__ float red[256];
  int t = blockIdx.x, tid = threadIdx.x;
  const float* row = X + (size_t)t * HIDN;
  float x[8];
  {
    float4 a = *(const float4*)(row + tid * 8);
    float4 b = *(const float4*)(row + tid * 8 + 4);
    x[0]=a.x; x[1]=a.y; x[2]=a.z; x[3]=a.w; x[4]=b.x; x[5]=b.y; x[6]=b.z; x[7]=b.w;
  }
  float s = 0.f;
#pragma unroll
  for (int j = 0; j < 8; j++) s += x[j];
  red[tid] = s; __syncthreads();
  for (int o = 128; o > 0; o >>= 1) { if (tid < o) red[tid] += red[tid + o]; __syncthreads(); }
  float mu = red[0] * (1.0f / HIDN);
  __syncthreads();
  float ss = 0.f;
#pragma unroll
  for (int j = 0; j < 8; j++) { float d = x[j] - mu; ss += d * d; }
  red[tid] = ss; __syncthreads();
  for (int o = 128; o > 0; o >>= 1) { if (tid < o) red[tid] += red[tid + o]; __syncthreads(); }
  float var = red[0] * (1.0f / HIDN);
  float rstd = 1.0f / sqrtf(var + 1e-5f);
#pragma unroll
  for (int j = 0; j < 8; j++) {
    int hh = tid * 8 + j;
    float y = (x[j] - mu) * rstd * W[hh] + Bi[hh];
    size_t idx = (size_t)t * HIDN + hh;
    if (Yf) Yf[idx] = y;
    unsigned short hv = f2bf(y);
    Yh[idx] = hv;
    if (Yl) Yl[idx] = f2bf(y - bf2f(hv));
  }
}

// ---------------- fused MoE front-end: h1 = hs + p0 + p1; LN2; xb(bf16); gate logits
__global__ __launch_bounds__(256) void moe_front(
    const float* __restrict__ hs, const float* __restrict__ p,
    const float* __restrict__ W, const float* __restrict__ Bi,
    const float* __restrict__ GW,
    float* __restrict__ h1, unsigned short* __restrict__ xb, float* __restrict__ L) {
  __shared__ float red[256];
  __shared__ float redg[256][8];
  int t = blockIdx.x, tid = threadIdx.x;
  size_t rowo = (size_t)t * HIDN + tid * 8;
  const float* a0 = hs + rowo;
  const float* p0 = p + rowo;
  const float* p1 = p + (size_t)TTOK * HIDN + rowo;
  float x[8];
  {
    float4 a = *(const float4*)(a0);
    float4 b = *(const float4*)(a0 + 4);
    float4 c = *(const float4*)(p0);
    float4 d = *(const float4*)(p0 + 4);
    float4 e = *(const float4*)(p1);
    float4 f = *(const float4*)(p1 + 4);
    x[0] = a.x + c.x + e.x; x[1] = a.y + c.y + e.y; x[2] = a.z + c.z + e.z; x[3] = a.w + c.w + e.w;
    x[4] = b.x + d.x + f.x; x[5] = b.y + d.y + f.y; x[6] = b.z + d.z + f.z; x[7] = b.w + d.w + f.w;
  }
  {
    float4 o0; o0.x = x[0]; o0.y = x[1]; o0.z = x[2]; o0.w = x[3];
    float4 o1; o1.x = x[4]; o1.y = x[5]; o1.z = x[6]; o1.w = x[7];
    *(float4*)(h1 + rowo) = o0;
    *(float4*)(h1 + rowo + 4) = o1;
  }
  float s = 0.f;
#pragma unroll
  for (int j = 0; j < 8; j++) s += x[j];
  red[tid] = s; __syncthreads();
  for (int o = 128; o > 0; o >>= 1) { if (tid < o) red[tid] += red[tid + o]; __syncthreads(); }
  float mu = red[0] * (1.0f / HIDN);
  __syncthreads();
  float ss = 0.f;
#pragma unroll
  for (int j = 0; j < 8; j++) { float d = x[j] - mu; ss += d * d; }
  red[tid] = ss; __syncthreads();
  for (int o = 128; o > 0; o >>= 1) { if (tid < o) red[tid] += red[tid + o]; __syncthreads(); }
  float var = red[0] * (1.0f / HIDN);
  float rstd = 1.0f / sqrtf(var + 1e-5f);
  float acc[8] = {0.f,0.f,0.f,0.f,0.f,0.f,0.f,0.f};
  u16x8 xv;
#pragma unroll
  for (int j = 0; j < 8; j++) {
    int hh = tid * 8 + j;
    float y = (x[j] - mu) * rstd * W[hh] + Bi[hh];
    xv[j] = f2bf(y);
    const float* gp = GW + (size_t)hh * NEXP;
    float4 g0 = *(const float4*)gp;
    float4 g1 = *(const float4*)(gp + 4);
    acc[0] += y * g0.x; acc[1] += y * g0.y; acc[2] += y * g0.z; acc[3] += y * g0.w;
    acc[4] += y * g1.x; acc[5] += y * g1.y; acc[6] += y * g1.z; acc[7] += y * g1.w;
  }
  *(u16x8*)(xb + rowo) = xv;
#pragma unroll
  for (int k = 0; k < 8; k++) redg[tid][k] = acc[k];
  __syncthreads();
  for (int o = 128; o > 0; o >>= 1) {
    if (tid < o) {
#pragma unroll
      for (int k = 0; k < 8; k++) redg[tid][k] += redg[tid + o][k];
    }
    __syncthreads();
  }
  if (tid < 8) L[(size_t)t * NEXP + tid] = redg[0][tid];
}

// ---------------- weight split: fp32 -> bf16 hi/lo (streaming)
__global__ __launch_bounds__(256) void wsplit(const float* __restrict__ W,
    unsigned short* __restrict__ Wh, unsigned short* __restrict__ Wl) {
  size_t i = ((size_t)blockIdx.x * 256 + threadIdx.x) * 8;
  float4 a = *(const float4*)(W + i);
  float4 b = *(const float4*)(W + i + 4);
  float v[8] = {a.x, a.y, a.z, a.w, b.x, b.y, b.z, b.w};
  u16x8 hv, lv;
#pragma unroll
  for (int j = 0; j < 8; j++) {
    unsigned short h = f2bf(v[j]);
    hv[j] = h; lv[j] = f2bf(v[j] - bf2f(h));
  }
  *(u16x8*)(Wh + i) = hv;
  *(u16x8*)(Wl + i) = lv;
}

// ---------------- high-precision GEMM with split-K x2: C-slab[kh] = partial over K-half
// 1D grid, XCD-chunk swizzle. 64B rows, row-PAIR XOR chunk swizzle (2-way = free).
// Counted-vmcnt 2-deep pipeline.
__global__ __launch_bounds__(256) void gemm_x3s(
    const unsigned short* __restrict__ Ah, const unsigned short* __restrict__ Al,
    const unsigned short* __restrict__ Bh, const unsigned short* __restrict__ Bl,
    float* __restrict__ Cp, int M, int N, int K2, int ldk) {
  __shared__ __align__(16) unsigned short sAh[2][4096], sAl[2][4096], sBh[2][4096], sBl[2][4096];
  int tid = threadIdx.x;
  int nbm = M >> 7, nbn = N >> 7, per = nbm * nbn;
  int cpx = gridDim.x >> 3;
  int bid = blockIdx.x;
  int l = (bid & 7) * cpx + (bid >> 3);
  int kh = l / per;
  int r = l % per;
  int nb = r / nbm, mb = r % nbm;
  int m0 = mb * BM, n0 = nb * BM;
  size_t ko = (size_t)kh * K2;
  int wv = tid >> 6, lane = tid & 63;
  int wr = wv >> 1, wc = wv & 1;
  int lm = lane & 15, lk = lane >> 4;
  f32x4 acc[4][4];
#pragma unroll
  for (int mi = 0; mi < 4; mi++)
#pragma unroll
    for (int ni = 0; ni < 4; ni++) { acc[mi][ni][0]=0.f; acc[mi][ni][1]=0.f; acc[mi][ni][2]=0.f; acc[mi][ni][3]=0.f; }
  int ri = lane >> 2, ccx = lane & 3;
  int swze = (ccx ^ ((ri >> 1) & 3)) * 8;   // row-PAIR swizzle
  int g0 = wv * 2, g1 = g0 + 1;
  const unsigned short* pah0 = Ah + (size_t)(m0 + g0 * 16 + ri) * ldk + ko + swze;
  const unsigned short* pah1 = Ah + (size_t)(m0 + g1 * 16 + ri) * ldk + ko + swze;
  const unsigned short* pal0 = Al + (size_t)(m0 + g0 * 16 + ri) * ldk + ko + swze;
  const unsigned short* pal1 = Al + (size_t)(m0 + g1 * 16 + ri) * ldk + ko + swze;
  const unsigned short* pbh0 = Bh + (size_t)(n0 + g0 * 16 + ri) * ldk + ko + swze;
  const unsigned short* pbh1 = Bh + (size_t)(n0 + g1 * 16 + ri) * ldk + ko + swze;
  const unsigned short* pbl0 = Bl + (size_t)(n0 + g0 * 16 + ri) * ldk + ko + swze;
  const unsigned short* pbl1 = Bl + (size_t)(n0 + g1 * 16 + ri) * ldk + ko + swze;
  int d0 = g0 * 512, d1 = g1 * 512;
  auto stage = [&](int buf, int ks) {        // 8 gl_lds per wave
    gl_lds16(pah0 + ks, &sAh[buf][d0]); gl_lds16(pah1 + ks, &sAh[buf][d1]);
    gl_lds16(pal0 + ks, &sAl[buf][d0]); gl_lds16(pal1 + ks, &sAl[buf][d1]);
    gl_lds16(pbh0 + ks, &sBh[buf][d0]); gl_lds16(pbh1 + ks, &sBh[buf][d1]);
    gl_lds16(pbl0 + ks, &sBl[buf][d0]); gl_lds16(pbl1 + ks, &sBl[buf][d1]);
  };
  int nt = K2 / BKS;
  stage(0, 0);
  stage(1, BKS);
  int sa = (lk ^ ((lm >> 1) & 3)) * 8;      // read swizzle
  for (int t = 0; t < nt; t++) {
    if (t + 1 < nt) { asm volatile("s_waitcnt vmcnt(8)" ::: "memory"); }
    else            { asm volatile("s_waitcnt vmcnt(0)" ::: "memory"); }
    __builtin_amdgcn_sched_barrier(0);
    __builtin_amdgcn_s_barrier();
    int cur = t & 1;
    bf16x8 fah[4], fal[4], fbh[4], fbl[4];
#pragma unroll
    for (int mi = 0; mi < 4; mi++) {
      int ro = (wr * 64 + mi * 16 + lm) * 32 + sa;
      fah[mi] = ldbf8(&sAh[cur][ro]); fal[mi] = ldbf8(&sAl[cur][ro]);
    }
#pragma unroll
    for (int ni = 0; ni < 4; ni++) {
      int ro = (wc * 64 + ni * 16 + lm) * 32 + sa;
      fbh[ni] = ldbf8(&sBh[cur][ro]); fbl[ni] = ldbf8(&sBl[cur][ro]);
    }
#pragma unroll
    for (int mi = 0; mi < 4; mi++)
#pragma unroll
      for (int ni = 0; ni < 4; ni++) {
        acc[mi][ni] = mfma16(fah[mi], fbh[ni], acc[mi][ni]);
        acc[mi][ni] = mfma16(fal[mi], fbh[ni], acc[mi][ni]);
        acc[mi][ni] = mfma16(fah[mi], fbl[ni], acc[mi][ni]);
      }
    __builtin_amdgcn_s_barrier();
    if (t + 2 < nt) stage(cur, (t + 2) * BKS);
  }
  float* Cslab = Cp + (size_t)kh * M * N;
#pragma unroll
  for (int mi = 0; mi < 4; mi++)
#pragma unroll
    for (int ni = 0; ni < 4; ni++)
#pragma unroll
      for (int rr = 0; rr < 4; rr++) {
        int row = m0 + wr * 64 + mi * 16 + lk * 4 + rr;
        int col = n0 + wc * 64 + ni * 16 + lm;
        Cslab[(size_t)row * N + col] = acc[mi][ni][rr];
      }
}

// ---------------- Fused-transpose MoE GEMM: C[z] = A[z][M,K](bf16) * B[z][K,N](fp32)
// R22: BK=32, 32KB LDS total -> 5 blocks/CU (was 2). Same loop/barrier structure.
// Swizzle for 64B rows (4 chunks): store global chunk c at LDS chunk c^((row>>2)&3);
// read positions (lm&1, lk^(lm>>2)) = 8 slots x 2 lanes = 2-way = free.
// A: gl_lds (2/wave). B: fp32 read to regs, cvt_pk, one b128 write per (thread,i).
template<int GELU, int SPLITK>
__global__ __launch_bounds__(256) void gemm_moeF(
    const unsigned short* __restrict__ A, const float* __restrict__ Bsrc,
    void* __restrict__ Cp, int M, int N, int K, int ldA, int ldB) {
  __shared__ __align__(16) unsigned short sA[2][4096], sB[2][4096];
  int tid = threadIdx.x;
  int nbm = M >> 7, nbn = N >> 7, per = nbm * nbn;
  int cpx = gridDim.x >> 3;
  int bid = blockIdx.x;
  int l = (bid & 7) * cpx + (bid >> 3);
  int z = l / per;
  int r = l % per;
  int nb = r / nbm, mb = r % nbm;
  int m0 = mb * BM, n0 = nb * BM;
  const unsigned short* Az;
  const float* Bz;
  if (SPLITK) {
    int e = z >> 1, kh = z & 1;
    Az = A + (size_t)e * M * ldA + (size_t)kh * K;
    Bz = Bsrc + (size_t)e * (2 * (size_t)K) * ldB + (size_t)kh * K * ldB;
  } else {
    Az = A + (size_t)z * M * ldA;
    Bz = Bsrc + (size_t)z * (size_t)K * ldB;
  }
  int wv = tid >> 6, lane = tid & 63;
  int wr = wv >> 1, wc = wv & 1;
  int lm = lane & 15, lk = lane >> 4;
  f32x4 acc[4][4];
#pragma unroll
  for (int mi = 0; mi < 4; mi++)
#pragma unroll
    for (int ni = 0; ni < 4; ni++) { acc[mi][ni][0]=0.f; acc[mi][ni][1]=0.f; acc[mi][ni][2]=0.f; acc[mi][ni][3]=0.f; }
  // A staging: 8 groups of 16 rows (64B each); wave wv stages groups 2wv, 2wv+1 (2 gl_lds/wave)
  int ri = lane >> 2, cc4 = lane & 3;
  int swzeA = (cc4 ^ ((ri >> 2) & 3)) * 8;     // source chunk = dest chunk ^ ((row>>2)&3)
  const unsigned short* pa[2];
#pragma unroll
  for (int j = 0; j < 2; j++)
    pa[j] = Az + (size_t)(m0 + (wv * 2 + j) * 16 + ri) * ldA + swzeA;
  int dbaseA = wv * 2 * 512;                   // 16 rows x 32 u16 = 512 u16 per group
  auto stageA = [&](int buf, int ks) {
#pragma unroll
    for (int j = 0; j < 2; j++)
      gl_lds16(pa[j] + ks, &sA[buf][dbaseA + j * 512]);
  };
  // B staging: thread covers k-chunk cpb (8 k's) for n = nh*64 + i*32 + tq (i=0..1)
  int tq = tid & 31;
  int cpb = (tid >> 5) & 3;         // the single k-chunk this thread owns
  int nh = tid >> 7;                // n-half
  float bs[16];                      // bs[kk*2+i]: k-row kk (0..7), n-index i (0..1)
  auto issueB = [&](int ks) {
#pragma unroll
    for (int kk = 0; kk < 8; kk++)
#pragma unroll
      for (int i = 0; i < 2; i++)
        bs[kk * 2 + i] = Bz[(size_t)(ks + cpb * 8 + kk) * ldB + n0 + nh * 64 + i * 32 + tq];
  };
  auto cvtwriteB = [&](int buf) {
    unsigned short* dB = &sB[buf][0];
#pragma unroll
    for (int i = 0; i < 2; i++) {
      int n = nh * 64 + i * 32 + tq;
      unsigned int p0 = cvt_pk_bf16(bs[0 * 2 + i], bs[1 * 2 + i]);
      unsigned int p1 = cvt_pk_bf16(bs[2 * 2 + i], bs[3 * 2 + i]);
      unsigned int p2 = cvt_pk_bf16(bs[4 * 2 + i], bs[5 * 2 + i]);
      unsigned int p3 = cvt_pk_bf16(bs[6 * 2 + i], bs[7 * 2 + i]);
      uint4 w; w.x = p0; w.y = p1; w.z = p2; w.w = p3;
      *(uint4*)&dB[n * 32 + ((cpb ^ ((n >> 2) & 3)) * 8)] = w;   // one b128 write
    }
  };
  int nt = K / BKM;
  // prologue: tile 0
  stageA(0, 0);
  issueB(0);
  asm volatile("s_waitcnt vmcnt(0)" ::: "memory");
  __builtin_amdgcn_sched_barrier(0);
  cvtwriteB(0);
  __syncthreads();
  int swm = (lm >> 2) & 3;
  int sa = (lk ^ swm) * 8;          // read swizzle (global chunk lk at LDS chunk lk^((row>>2)&3))
  for (int t = 0; t < nt; t++) {
    int cur = t & 1;
    bool more = (t + 1 < nt);
    if (more) {
      stageA(cur ^ 1, (t + 1) * BKM);     // writes buf[cur^1]: readers done at iter t-1
      issueB((t + 1) * BKM);
      __builtin_amdgcn_sched_barrier(0);  // pin load issue before compute
    }
    {
      bf16x8 fa[4], fb[4];
#pragma unroll
      for (int mi = 0; mi < 4; mi++) fa[mi] = ldbf8(&sA[cur][(wr * 64 + mi * 16 + lm) * 32 + sa]);
#pragma unroll
      for (int ni = 0; ni < 4; ni++) fb[ni] = ldbf8(&sB[cur][(wc * 64 + ni * 16 + lm) * 32 + sa]);
#pragma unroll
      for (int mi = 0; mi < 4; mi++)
#pragma unroll
        for (int ni = 0; ni < 4; ni++)
          acc[mi][ni] = mfma16(fa[mi], fb[ni], acc[mi][ni]);
    }
    if (more) {
      asm volatile("s_waitcnt vmcnt(0)" ::: "memory");   // A(t+1) landed in LDS, B(t+1) in regs
      __builtin_amdgcn_sched_barrier(0);
      cvtwriteB(cur ^ 1);                 // writes buf[cur^1]: no reader this iter
      __syncthreads();                    // single barrier: publish A+B(t+1); order next iter's writes
    }
  }
#pragma unroll
  for (int mi = 0; mi < 4; mi++)
#pragma unroll
    for (int ni = 0; ni < 4; ni++)
#pragma unroll
      for (int rr = 0; rr < 4; rr++) {
        int row = m0 + wr * 64 + mi * 16 + lk * 4 + rr;
        int col = n0 + wc * 64 + ni * 16 + lm;
        size_t idx = (size_t)z * M * N + (size_t)row * N + col;
        float v = acc[mi][ni][rr];
        if (GELU) {
          float gv = 0.5f * v * (1.0f + erff(v * 0.70710678118654752f));
          ((unsigned short*)Cp)[idx] = f2bf(gv);
        } else {
          ((float*)Cp)[idx] = v;
        }
      }
}

// ---------------- repack qkv partial slabs (sum) -> Q/K (bf16 hi/lo) and V^T (bf16 hi/lo)
__global__ __launch_bounds__(256) void repack_kernel(
    const float* __restrict__ qkvp,
    unsigned short* __restrict__ Qh, unsigned short* __restrict__ Ql,
    unsigned short* __restrict__ Kh, unsigned short* __restrict__ Kl,
    unsigned short* __restrict__ Vh, unsigned short* __restrict__ Vl) {
  int t = blockIdx.x; int s = t / BATCH, b = t % BATCH;
  const float* row0 = qkvp + (size_t)t * QKVSZ;
  const float* row1 = row0 + (size_t)TTOK * QKVSZ;
  int tid = threadIdx.x;
  for (int idx = tid; idx < 2048; idx += 256) {
    int hh = idx >> 7, d = idx & 127;
    int o_in = (hh >> 2) * GRP + (hh & 3) * 128 + d;
    float val = row0[o_in] + row1[o_in];
    unsigned short hv = f2bf(val), lv = f2bf(val - bf2f(hv));
    size_t o = ((size_t)(b * NHEAD + hh) * S_LEN + s) * HDIM + d;
    Qh[o] = hv; Ql[o] = lv;
  }
  for (int idx = tid; idx < 512; idx += 256) {
    int g = idx >> 7, d = idx & 127;
    int o_in = g * GRP + 512 + d;
    float val = row0[o_in] + row1[o_in];
    unsigned short hv = f2bf(val), lv = f2bf(val - bf2f(hv));
    size_t o = ((size_t)(b * KVHN + g) * S_LEN + s) * HDIM + d;
    Kh[o] = hv; Kl[o] = lv;
  }
  for (int idx = tid; idx < 512; idx += 256) {
    int g = idx >> 7, d = idx & 127;
    int o_in = g * GRP + 640 + d;
    float val = row0[o_in] + row1[o_in];
    unsigned short hv = f2bf(val), lv = f2bf(val - bf2f(hv));
    size_t o = ((size_t)(b * KVHN + g) * HDIM + d) * S_LEN + s;
    Vh[o] = hv; Vl[o] = lv;
  }
}

// ---------------- causal flash attention: 1 block = 4 waves = 4 heads of one KV group,
// 16-query tile; K chunk (hi+lo) staged in LDS via gl_lds dbuf with XOR-swizzled source.
__global__ __launch_bounds__(256) void attn4(
    const unsigned short* __restrict__ Qh, const unsigned short* __restrict__ Ql,
    const unsigned short* __restrict__ Kh, const unsigned short* __restrict__ Kl,
    const unsigned short* __restrict__ Vh, const unsigned short* __restrict__ Vl,
    unsigned short* __restrict__ Oh, unsigned short* __restrict__ Ol) {
  __shared__ __align__(16) unsigned short sK[2][2][32 * 128];       // [buf][hi/lo][key][d^swz]
  __shared__ __align__(16) unsigned short Ph[4][2][16 * LDT], Pl[4][2][16 * LDT];
  int qt = blockIdx.x, g = blockIdx.y, b = blockIdx.z;
  int tid = threadIdx.x, wv = tid >> 6, lane = tid & 63;
  int lm = lane & 15, lk = lane >> 4;
  int hh = g * 4 + wv;
  int q0 = qt * 16;
  const float scale = 0.08838834764831845f;  // 1/sqrt(128)
  int r0 = wv * 4 + (lane >> 4);
  int c16 = lane & 15;
  int dsw = (c16 * 8) ^ ((r0 & 7) << 3);
  const unsigned short* kbh = Kh + (size_t)((b * KVHN + g) * S_LEN) * HDIM;
  const unsigned short* kbl = Kl + (size_t)((b * KVHN + g) * S_LEN) * HDIM;
  auto stageK = [&](int buf, int k0) {
    unsigned short* dh = &sK[buf][0][0];
    unsigned short* dl = &sK[buf][1][0];
    gl_lds16(kbh + (size_t)(k0 + r0) * HDIM + dsw,      dh + wv * 512);
    gl_lds16(kbh + (size_t)(k0 + r0 + 16) * HDIM + dsw, dh + 2048 + wv * 512);
    gl_lds16(kbl + (size_t)(k0 + r0) * HDIM + dsw,      dl + wv * 512);
    gl_lds16(kbl + (size_t)(k0 + r0 + 16) * HDIM + dsw, dl + 2048 + wv * 512);
  };
  bf16x8 qfh[4], qfl[4];
  {
    size_t qb = ((size_t)(b * NHEAD + hh) * S_LEN + q0 + lm) * HDIM + lk * 8;
#pragma unroll
    for (int dc = 0; dc < 4; dc++) {
      qfh[dc] = ldbf8(Qh + qb + dc * 32);
      qfl[dc] = ldbf8(Ql + qb + dc * 32);
    }
  }
  f32x4 accO[8];
#pragma unroll
  for (int dt = 0; dt < 8; dt++) { accO[dt][0]=0.f; accO[dt][1]=0.f; accO[dt][2]=0.f; accO[dt][3]=0.f; }
  float mrun = -3.4e38f, lrun = 0.f;
  int nch = (q0 + 47) >> 5;
  stageK(0, 0);
  asm volatile("s_waitcnt vmcnt(0)" ::: "memory");
  __syncthreads();
  int cur = 0;
  for (int ck = 0; ck < nch; ck++) {
    int k0 = ck * 32;
    if (ck + 1 < nch) stageK(cur ^ 1, k0 + 32);
    f32x4 sc[2];
    sc[0][0]=0.f; sc[0][1]=0.f; sc[0][2]=0.f; sc[0][3]=0.f;
    sc[1][0]=0.f; sc[1][1]=0.f; sc[1][2]=0.f; sc[1][3]=0.f;
#pragma unroll
    for (int t2 = 0; t2 < 2; t2++) {
      int row = t2 * 16 + lm;
#pragma unroll
      for (int dc = 0; dc < 4; dc++) {
        int ce = (dc * 32 + lk * 8) ^ ((row & 7) << 3);
        bf16x8 kfh = ldbf8(&sK[cur][0][row * 128 + ce]);
        bf16x8 kfl = ldbf8(&sK[cur][1][row * 128 + ce]);
        sc[t2] = mfma16(kfh, qfh[dc], sc[t2]);
        sc[t2] = mfma16(kfl, qfh[dc], sc[t2]);
        sc[t2] = mfma16(kfh, qfl[dc], sc[t2]);
      }
    }
    float pv[8];
    float pmax = -3.4e38f;
#pragma unroll
    for (int t2 = 0; t2 < 2; t2++)
#pragma unroll
      for (int rr = 0; rr < 4; rr++) {
        int key = k0 + t2 * 16 + lk * 4 + rr;
        float sv = sc[t2][rr] * scale;
        if (key > q0 + lm) sv = -3.4e38f;
        pv[t2 * 4 + rr] = sv;
        pmax = fmaxf(pmax, sv);
      }
    pmax = fmaxf(pmax, __shfl_xor(pmax, 16));
    pmax = fmaxf(pmax, __shfl_xor(pmax, 32));
    float mnew = fmaxf(mrun, pmax);
    float fsc = expf(mrun - mnew);
    float psum = 0.f;
#pragma unroll
    for (int j = 0; j < 8; j++) { pv[j] = expf(pv[j] - mnew); psum += pv[j]; }
    psum = psum + __shfl_xor(psum, 16);
    psum = psum + __shfl_xor(psum, 32);
    lrun = lrun * fsc + psum;
#pragma unroll
    for (int dt = 0; dt < 8; dt++)
#pragma unroll
      for (int rr = 0; rr < 4; rr++) accO[dt][rr] *= fsc;
    int pb = ck & 1;
#pragma unroll
    for (int t2 = 0; t2 < 2; t2++) {
      u16x4 wh, wl;
#pragma unroll
      for (int rr = 0; rr < 4; rr++) {
        float p = pv[t2 * 4 + rr];
        unsigned short hv = f2bf(p);
        wh[rr] = hv; wl[rr] = f2bf(p - bf2f(hv));
      }
      int ad = lm * LDT + t2 * 16 + lk * 4;
      *(u16x4*)&Ph[wv][pb][ad] = wh;
      *(u16x4*)&Pl[wv][pb][ad] = wl;
    }
    bf16x8 pfh = ldbf8(&Ph[wv][pb][lm * LDT + lk * 8]);
    bf16x8 pfl = ldbf8(&Pl[wv][pb][lm * LDT + lk * 8]);
#pragma unroll
    for (int dt = 0; dt < 8; dt++) {
      size_t vo = ((size_t)((b * KVHN + g) * HDIM + dt * 16 + lm)) * S_LEN + k0 + lk * 8;
      bf16x8 vfh = ldbf8(Vh + vo);
      bf16x8 vfl = ldbf8(Vl + vo);
      accO[dt] = mfma16(vfh, pfh, accO[dt]);
      accO[dt] = mfma16(vfl, pfh, accO[dt]);
      accO[dt] = mfma16(vfh, pfl, accO[dt]);
    }
    mrun = mnew;
    asm volatile("s_waitcnt vmcnt(0)" ::: "memory");
    __syncthreads();
    cur ^= 1;
  }
  float inv = 1.0f / lrun;
#pragma unroll
  for (int dt = 0; dt < 8; dt++)
#pragma unroll
    for (int rr = 0; rr < 4; rr++) {
      float o = accO[dt][rr] * inv;
      int d = dt * 16 + lk * 4 + rr;
      int srow = q0 + lm;
      size_t idx = ((size_t)(srow * BATCH + b)) * HIDN + hh * HDIM + d;
      unsigned short hv = f2bf(o);
      Oh[idx] = hv; Ol[idx] = f2bf(o - bf2f(hv));
    }
}

// ---------------- routing: softmax, top-2 (first-max semantics), capacity cumsum, scatter
__global__ __launch_bounds__(1024) void routing_kernel(
    const float* __restrict__ L, int* __restrict__ slot_token,
    int* __restrict__ tE1, int* __restrict__ tP1, float* __restrict__ tG1,
    int* __restrict__ tE2, int* __restrict__ tP2, float* __restrict__ tG2) {
  __shared__ unsigned int sc[1024][8];
  __shared__ unsigned int stot[8];
  int i = threadIdx.x;
  for (int j = i; j < NEXP * CAPC; j += 1024) slot_token[j] = -1;

  int e1[2], e2[2]; float g1[2], g2[2];
  unsigned int v[8] = {0,0,0,0,0,0,0,0};
#pragma unroll
  for (int u = 0; u < 2; u++) {
    int t = 2 * i + u;
    float l[8];
    float m = -3.4e38f;
#pragma unroll
    for (int e = 0; e < 8; e++) { l[e] = L[(size_t)t * NEXP + e]; m = fmaxf(m, l[e]); }
    float ex[8]; float se = 0.f;
#pragma unroll
    for (int e = 0; e < 8; e++) { ex[e] = expf(l[e] - m); se += ex[e]; }
    int b1 = 0; float bv = l[0];
    for (int e = 1; e < 8; e++) if (l[e] > bv) { bv = l[e]; b1 = e; }
    int b2 = -1; float bv2 = 0.f;
    for (int e = 0; e < 8; e++) {
      if (e == b1) continue;
      if (b2 < 0 || l[e] > bv2) { b2 = e; bv2 = l[e]; }
    }
    e1[u] = b1; e2[u] = b2;
    g1[u] = ex[b1] / se; g2[u] = ex[b2] / se;
    v[b1 >> 1] += 1u << ((b1 & 1) * 16);
    v[4 + (b2 >> 1)] += 1u << ((b2 & 1) * 16);
  }
  unsigned int cur[8];
#pragma unroll
  for (int k = 0; k < 8; k++) cur[k] = v[k];
  for (int off = 1; off < 1024; off <<= 1) {
#pragma unroll
    for (int k = 0; k < 8; k++) sc[i][k] = cur[k];
    __syncthreads();
    if (i >= off) {
#pragma unroll
      for (int k = 0; k < 8; k++) cur[k] += sc[i - off][k];
    }
    __syncthreads();
  }
  if (i == 1023) {
#pragma unroll
    for (int k = 0; k < 8; k++) stot[k] = cur[k];
  }
  __syncthreads();
  unsigned int excl[8];
#pragma unroll
  for (int k = 0; k < 8; k++) excl[k] = cur[k] - v[k];

#pragma unroll
  for (int u = 0; u < 2; u++) {
    int t = 2 * i + u;
    int a1 = e1[u], a2 = e2[u];
    int loc1 = (int)((excl[a1 >> 1] >> ((a1 & 1) * 16)) & 0xFFFFu);
    int loc2 = (int)((excl[4 + (a2 >> 1)] >> ((a2 & 1) * 16)) & 0xFFFFu);
    if (u == 1) {
      if (a1 == e1[0]) loc1 += 1;
      if (a2 == e2[0]) loc2 += 1;
    }
    loc2 += (int)((stot[a2 >> 1] >> ((a2 & 1) * 16)) & 0xFFFFu);  // + total first-choice count
    bool k1 = loc1 < CAPC, k2 = loc2 < CAPC;
    float G1 = k1 ? g1[u] : 0.f, G2 = k2 ? g2[u] : 0.f;
    float den = fmaxf(G1 + G2, 1.1920929e-07f);
    G1 /= den; G2 /= den;
    tE1[t] = a1; tP1[t] = k1 ? loc1 : 0; tG1[t] = G1;
    tE2[t] = a2; tP2[t] = k2 ? loc2 : 0; tG2[t] = G2;
    if (k1) slot_token[a1 * CAPC + loc1] = t;
    if (k2) slot_token[a2 * CAPC + loc2] = t;
  }
}

// ---------------- gather tokens into expert capacity slots (bf16)
__global__ __launch_bounds__(256) void gather_kernel(
    const int* __restrict__ slot_token, const unsigned short* __restrict__ Xb,
    unsigned short* __restrict__ XE) {
  int slot = blockIdx.x;
  int t = slot_token[slot];
  unsigned short* dst = XE + (size_t)slot * HIDN + threadIdx.x * 8;
  if (t >= 0) {
    *(u16x8*)dst = *(const u16x8*)(Xb + (size_t)t * HIDN + threadIdx.x * 8);
  } else {
    u16x8 zz = {0,0,0,0,0,0,0,0};
    *(u16x8*)dst = zz;
  }
}

// ---------------- combine: out = h1 + g1*(eoA+eoB)[e1,p1] + g2*(eoA+eoB)[e2,p2]
// eo2 layout: [e*2 + kh][CAPC][HIDN] fp32 partials (split-K halves)
__global__ __launch_bounds__(256) void combine_kernel(
    const float* __restrict__ h1, const float* __restrict__ eo2,
    const int* __restrict__ tE1, const int* __restrict__ tP1, const float* __restrict__ tG1,
    const int* __restrict__ tE2, const int* __restrict__ tP2, const float* __restrict__ tG2,
    float* __restrict__ outp) {
  int t = blockIdx.x, tid = threadIdx.x;
  float G1 = tG1[t], G2 = tG2[t];
  size_t MN = (size_t)CAPC * HIDN;
  size_t b1 = ((size_t)tE1[t] * 2) * MN + (size_t)tP1[t] * HIDN;
  size_t b2 = ((size_t)tE2[t] * 2) * MN + (size_t)tP2[t] * HIDN;
  size_t rowo = (size_t)t * HIDN;
  int c = tid * 8;
#pragma unroll
  for (int j = 0; j < 8; j += 4) {
    float4 hv  = *(const float4*)(h1 + rowo + c + j);
    float4 e1a = *(const float4*)(eo2 + b1 + c + j);
    float4 e1b = *(const float4*)(eo2 + b1 + MN + c + j);
    float4 e2a = *(const float4*)(eo2 + b2 + c + j);
    float4 e2b = *(const float4*)(eo2 + b2 + MN + c + j);
    float4 o;
    o.x = hv.x + G1 * (e1a.x + e1b.x) + G2 * (e2a.x + e2b.x);
    o.y = hv.y + G1 * (e1a.y + e1b.y) + G2 * (e2a.y + e2b.y);
    o.z = hv.z + G1 * (e1a.z + e1b.z) + G2 * (e2a.z + e2b.z);
    o.w = hv.w + G1 * (e1a.w + e1b.w) + G2 * (e2a.w + e2b.w);
    *(float4*)(outp + rowo + c + j) = o;
  }
}

extern "C" void kernel_launch(void* const* d_in, const int* in_sizes, int n_in,
                              void* d_out, int out_size, void* d_ws, size_t ws_size,
                              hipStream_t stream) {
  const float* hs    = (const float*)d_in[0];
  const float* ln1w  = (const float*)d_in[1];
  const float* ln1b  = (const float*)d_in[2];
  const float* qkvw  = (const float*)d_in[3];
  const float* projw = (const float*)d_in[4];
  const float* ln2w  = (const float*)d_in[5];
  const float* ln2b  = (const float*)d_in[6];
  const float* gatew = (const float*)d_in[7];
  const float* w1    = (const float*)d_in[8];
  const float* w2    = (const float*)d_in[9];
  float* outp = (float*)d_out;

  char* base = (char*)d_ws;
  size_t off = 0;
  auto alloc = [&](size_t bytes) -> void* {
    void* r = base + off;
    off = (off + bytes + 255) & ~(size_t)255;
    return r;
  };
  unsigned short* ln1h = (unsigned short*)alloc((size_t)TTOK * HIDN * 2);
  unsigned short* ln1l = (unsigned short*)alloc((size_t)TTOK * HIDN * 2);
  float* qkvp = (float*)alloc((size_t)2 * TTOK * QKVSZ * 4);          // split-K partial slabs
  unsigned short* Qh = (unsigned short*)alloc((size_t)BATCH * NHEAD * S_LEN * HDIM * 2);
  unsigned short* Ql = (unsigned short*)alloc((size_t)BATCH * NHEAD * S_LEN * HDIM * 2);
  unsigned short* Kh = (unsigned short*)alloc((size_t)BATCH * KVHN * S_LEN * HDIM * 2);
  unsigned short* Kl = (unsigned short*)alloc((size_t)BATCH * KVHN * S_LEN * HDIM * 2);
  unsigned short* Vh = (unsigned short*)alloc((size_t)BATCH * KVHN * S_LEN * HDIM * 2);
  unsigned short* Vl = (unsigned short*)alloc((size_t)BATCH * KVHN * S_LEN * HDIM * 2);
  unsigned short* oh = (unsigned short*)alloc((size_t)TTOK * HIDN * 2);
  unsigned short* ol = (unsigned short*)alloc((size_t)TTOK * HIDN * 2);
  float* h1p = (float*)alloc((size_t)2 * TTOK * HIDN * 4);            // proj partial slabs
  float* h1 = (float*)alloc((size_t)TTOK * HIDN * 4);
  unsigned short* xb = (unsigned short*)alloc((size_t)TTOK * HIDN * 2);
  float* logits = (float*)alloc((size_t)TTOK * NEXP * 4);
  int* slot = (int*)alloc((size_t)NEXP * CAPC * 4);
  int* tE1 = (int*)alloc((size_t)TTOK * 4);
  int* tP1 = (int*)alloc((size_t)TTOK * 4);
  int* tE2 = (int*)alloc((size_t)TTOK * 4);
  int* tP2 = (int*)alloc((size_t)TTOK * 4);
  float* tG1 = (float*)alloc((size_t)TTOK * 4);
  float* tG2 = (float*)alloc((size_t)TTOK * 4);
  unsigned short* xe = (unsigned short*)alloc((size_t)NEXP * CAPC * HIDN * 2);
  unsigned short* hmid = (unsigned short*)alloc((size_t)NEXP * CAPC * FFND * 2);
  float* eo2 = (float*)alloc((size_t)NEXP * 2 * CAPC * HIDN * 4);     // moe<0> split-K partials
  unsigned short* qwh = (unsigned short*)alloc((size_t)QKVSZ * HIDN * 2);
  unsigned short* qwl = (unsigned short*)alloc((size_t)QKVSZ * HIDN * 2);
  unsigned short* pwh = (unsigned short*)alloc((size_t)HIDN * HIDN * 2);
  unsigned short* pwl = (unsigned short*)alloc((size_t)HIDN * HIDN * 2);
  (void)ws_size; (void)in_sizes; (void)n_in; (void)out_size;

  // attention path
  ln_kernel<<<TTOK, 256, 0, stream>>>(hs, ln1w, ln1b, ln1h, ln1l, nullptr);
  wsplit<<<(QKVSZ * HIDN) / 2048, 256, 0, stream>>>(qkvw, qwh, qwl);
  wsplit<<<(HIDN * HIDN) / 2048, 256, 0, stream>>>(projw, pwh, pwl);
  // qkv: split-K x2 -> 768 blocks (3/CU)
  gemm_x3s<<<dim3((QKVSZ / BM) * (TTOK / BM) * 2), 256, 0, stream>>>(
      ln1h, ln1l, qwh, qwl, qkvp, TTOK, QKVSZ, HIDN / 2, HIDN);
  repack_kernel<<<TTOK, 256, 0, stream>>>(qkvp, Qh, Ql, Kh, Kl, Vh, Vl);
  attn4<<<dim3(S_LEN / 16, KVHN, BATCH), 256, 0, stream>>>(Qh, Ql, Kh, Kl, Vh, Vl, oh, ol);
  // proj: split-K x2 -> 512 blocks (2/CU)
  gemm_x3s<<<dim3((HIDN / BM) * (TTOK / BM) * 2), 256, 0, stream>>>(
      oh, ol, pwh, pwl, h1p, TTOK, HIDN, HIDN / 2, HIDN);
  // fused MoE front: h1 = hs + partials; LN2; xb; gate logits
  moe_front<<<TTOK, 256, 0, stream>>>(hs, h1p, ln2w, ln2b, gatew, h1, xb, logits);
  routing_kernel<<<1, 1024, 0, stream>>>(logits, slot, tE1, tP1, tG1, tE2, tP2, tG2);
  gather_kernel<<<NEXP * CAPC, 256, 0, stream>>>(slot, xb, xe);
  // moe<1>: fused-transpose, B = w1 fp32 [E][HIDN][FFND] read directly
  gemm_moeF<1, 0><<<dim3((FFND / BM) * (CAPC / BM) * NEXP), 256, 0, stream>>>(
      xe, w1, (void*)hmid, CAPC, FFND, HIDN, HIDN, FFND);
  // moe<0>: fused-transpose + split-K x2, B = w2 fp32 [E][FFND][HIDN]
  gemm_moeF<0, 1><<<dim3((HIDN / BM) * (CAPC / BM) * NEXP * 2), 256, 0, stream>>>(
      hmid, w2, (void*)eo2, CAPC, HIDN, FFND / 2, FFND, HIDN);
  combine_kernel<<<TTOK, 256, 0, stream>>>(h1, eo2, tE1, tP1, tG1, tE2, tP2, tG2, outp);
}

// Round 24
// 652.198 us; speedup vs baseline: 1.0774x; 1.0774x over previous
//
#include <hip/hip_runtime.h>
#include <math.h>

#define S_LEN 1024
#define BATCH 2
#define HIDN  2048
#define NHEAD 16
#define KVHN  4
#define HDIM  128
#define FFND  4096
#define NEXP  8
#define CAPC  512
#define TTOK  2048
#define QKVSZ 3072
#define GRP   768

#define BM  128
#define BKS 32   // K-step for gemm_x3s
#define BKM 64   // K-step for gemm_moeF (R23: reverted to 64; BK=32 regressed — conflicts + no occupancy gain)
#define LDT 40   // LDS row stride for attention P tiles

typedef float           f32x4 __attribute__((ext_vector_type(4)));
typedef __bf16          bf16x8 __attribute__((ext_vector_type(8)));
typedef unsigned short  u16x8 __attribute__((ext_vector_type(8)));
typedef unsigned short  u16x4 __attribute__((ext_vector_type(4)));

static __device__ __forceinline__ unsigned short f2bf(float f) {
  unsigned int u = __builtin_bit_cast(unsigned int, f);
  u += 0x7FFFu + ((u >> 16) & 1u);          // RTNE
  return (unsigned short)(u >> 16);
}
static __device__ __forceinline__ float bf2f(unsigned short h) {
  unsigned int u = ((unsigned int)h) << 16;
  return __builtin_bit_cast(float, u);
}
// one-instruction packed f32x2 -> bf16x2 (RTNE, matches f2bf)
static __device__ __forceinline__ unsigned int cvt_pk_bf16(float lo, float hi) {
  unsigned int r;
  asm("v_cvt_pk_bf16_f32 %0, %1, %2" : "=v"(r) : "v"(lo), "v"(hi));
  return r;
}
static __device__ __forceinline__ bf16x8 ldbf8(const unsigned short* p) {
  return __builtin_bit_cast(bf16x8, *(const u16x8*)p);
}
static __device__ __forceinline__ f32x4 mfma16(bf16x8 a, bf16x8 b, f32x4 c) {
  return __builtin_amdgcn_mfma_f32_16x16x32_bf16(a, b, c, 0, 0, 0);
}
// async global->LDS, 16B per lane; dest is wave-uniform base + lane*16
static __device__ __forceinline__ void gl_lds16(const unsigned short* g, unsigned short* l) {
  __builtin_amdgcn_global_load_lds(
      (const __attribute__((address_space(1))) unsigned int*)g,
      (__attribute__((address_space(3))) unsigned int*)l, 16, 0, 0);
}

// ---------------- LayerNorm (exact two-pass fp32), emits bf16 hi (+optional lo, +optional f32)
__global__ __launch_bounds__(256) void ln_kernel(
    const float* __restrict__ X, const float* __restrict__ W, const float* __restrict__ Bi,
    unsigned short* __restrict__ Yh, unsigned short* __restrict__ Yl, float* __restrict__ Yf) {
  __shared__ float red[256];
  int t = blockIdx.x, tid = threadIdx.x;
  const float* row = X + (size_t)t * HIDN;
  float x[8];
  {
    float4 a = *(const float4*)(row + tid * 8);
    float4 b = *(const float4*)(row + tid * 8 + 4);
    x[0]=a.x; x[1]=a.y; x[2]=a.z; x[3]=a.w; x[4]=b.x; x[5]=b.y; x[6]=b.z; x[7]=b.w;
  }
  float s = 0.f;
#pragma unroll
  for (int j = 0; j < 8; j++) s += x[j];
  red[tid] = s; __syncthreads();
  for (int o = 128; o > 0; o >>= 1) { if (tid < o) red[tid] += red[tid + o]; __syncthreads(); }
  float mu = red[0] * (1.0f / HIDN);
  __syncthreads();
  float ss = 0.f;
#pragma unroll
  for (int j = 0; j < 8; j++) { float d = x[j] - mu; ss += d * d; }
  red[tid] = ss; __syncthreads();
  for (int o = 128; o > 0; o >>= 1) { if (tid < o) red[tid] += red[tid + o]; __syncthreads(); }
  float var = red[0] * (1.0f / HIDN);
  float rstd = 1.0f / sqrtf(var + 1e-5f);
#pragma unroll
  for (int j = 0; j < 8; j++) {
    int hh = tid * 8 + j;
    float y = (x[j] - mu) * rstd * W[hh] + Bi[hh];
    size_t idx = (size_t)t * HIDN + hh;
    if (Yf) Yf[idx] = y;
    unsigned short hv = f2bf(y);
    Yh[idx] = hv;
    if (Yl) Yl[idx] = f2bf(y - bf2f(hv));
  }
}

// ---------------- fused MoE front-end: h1 = hs + p0 + p1; LN2; xb(bf16); gate logits
__global__ __launch_bounds__(256) void moe_front(
    const float* __restrict__ hs, const float* __restrict__ p,
    const float* __restrict__ W, const float* __restrict__ Bi,
    const float* __restrict__ GW,
    float* __restrict__ h1, unsigned short* __restrict__ xb, float* __restrict__ L) {
  __shared__ float red[256];
  __shared__ float redg[256][8];
  int t = blockIdx.x, tid = threadIdx.x;
  size_t rowo = (size_t)t * HIDN + tid * 8;
  const float* a0 = hs + rowo;
  const float* p0 = p + rowo;
  const float* p1 = p + (size_t)TTOK * HIDN + rowo;
  float x[8];
  {
    float4 a = *(const float4*)(a0);
    float4 b = *(const float4*)(a0 + 4);
    float4 c = *(const float4*)(p0);
    float4 d = *(const float4*)(p0 + 4);
    float4 e = *(const float4*)(p1);
    float4 f = *(const float4*)(p1 + 4);
    x[0] = a.x + c.x + e.x; x[1] = a.y + c.y + e.y; x[2] = a.z + c.z + e.z; x[3] = a.w + c.w + e.w;
    x[4] = b.x + d.x + f.x; x[5] = b.y + d.y + f.y; x[6] = b.z + d.z + f.z; x[7] = b.w + d.w + f.w;
  }
  {
    float4 o0; o0.x = x[0]; o0.y = x[1]; o0.z = x[2]; o0.w = x[3];
    float4 o1; o1.x = x[4]; o1.y = x[5]; o1.z = x[6]; o1.w = x[7];
    *(float4*)(h1 + rowo) = o0;
    *(float4*)(h1 + rowo + 4) = o1;
  }
  float s = 0.f;
#pragma unroll
  for (int j = 0; j < 8; j++) s += x[j];
  red[tid] = s; __syncthreads();
  for (int o = 128; o > 0; o >>= 1) { if (tid < o) red[tid] += red[tid + o]; __syncthreads(); }
  float mu = red[0] * (1.0f / HIDN);
  __syncthreads();
  float ss = 0.f;
#pragma unroll
  for (int j = 0; j < 8; j++) { float d = x[j] - mu; ss += d * d; }
  red[tid] = ss; __syncthreads();
  for (int o = 128; o > 0; o >>= 1) { if (tid < o) red[tid] += red[tid + o]; __syncthreads(); }
  float var = red[0] * (1.0f / HIDN);
  float rstd = 1.0f / sqrtf(var + 1e-5f);
  float acc[8] = {0.f,0.f,0.f,0.f,0.f,0.f,0.f,0.f};
  u16x8 xv;
#pragma unroll
  for (int j = 0; j < 8; j++) {
    int hh = tid * 8 + j;
    float y = (x[j] - mu) * rstd * W[hh] + Bi[hh];
    xv[j] = f2bf(y);
    const float* gp = GW + (size_t)hh * NEXP;
    float4 g0 = *(const float4*)gp;
    float4 g1 = *(const float4*)(gp + 4);
    acc[0] += y * g0.x; acc[1] += y * g0.y; acc[2] += y * g0.z; acc[3] += y * g0.w;
    acc[4] += y * g1.x; acc[5] += y * g1.y; acc[6] += y * g1.z; acc[7] += y * g1.w;
  }
  *(u16x8*)(xb + rowo) = xv;
#pragma unroll
  for (int k = 0; k < 8; k++) redg[tid][k] = acc[k];
  __syncthreads();
  for (int o = 128; o > 0; o >>= 1) {
    if (tid < o) {
#pragma unroll
      for (int k = 0; k < 8; k++) redg[tid][k] += redg[tid + o][k];
    }
    __syncthreads();
  }
  if (tid < 8) L[(size_t)t * NEXP + tid] = redg[0][tid];
}

// ---------------- weight split: fp32 -> bf16 hi/lo (streaming)
__global__ __launch_bounds__(256) void wsplit(const float* __restrict__ W,
    unsigned short* __restrict__ Wh, unsigned short* __restrict__ Wl) {
  size_t i = ((size_t)blockIdx.x * 256 + threadIdx.x) * 8;
  float4 a = *(const float4*)(W + i);
  float4 b = *(const float4*)(W + i + 4);
  float v[8] = {a.x, a.y, a.z, a.w, b.x, b.y, b.z, b.w};
  u16x8 hv, lv;
#pragma unroll
  for (int j = 0; j < 8; j++) {
    unsigned short h = f2bf(v[j]);
    hv[j] = h; lv[j] = f2bf(v[j] - bf2f(h));
  }
  *(u16x8*)(Wh + i) = hv;
  *(u16x8*)(Wl + i) = lv;
}

// ---------------- high-precision GEMM with split-K x2: C-slab[kh] = partial over K-half
// 1D grid, XCD-chunk swizzle. 64B rows, row-PAIR XOR chunk swizzle (2-way = free).
// Counted-vmcnt 2-deep pipeline.
__global__ __launch_bounds__(256) void gemm_x3s(
    const unsigned short* __restrict__ Ah, const unsigned short* __restrict__ Al,
    const unsigned short* __restrict__ Bh, const unsigned short* __restrict__ Bl,
    float* __restrict__ Cp, int M, int N, int K2, int ldk) {
  __shared__ __align__(16) unsigned short sAh[2][4096], sAl[2][4096], sBh[2][4096], sBl[2][4096];
  int tid = threadIdx.x;
  int nbm = M >> 7, nbn = N >> 7, per = nbm * nbn;
  int cpx = gridDim.x >> 3;
  int bid = blockIdx.x;
  int l = (bid & 7) * cpx + (bid >> 3);
  int kh = l / per;
  int r = l % per;
  int nb = r / nbm, mb = r % nbm;
  int m0 = mb * BM, n0 = nb * BM;
  size_t ko = (size_t)kh * K2;
  int wv = tid >> 6, lane = tid & 63;
  int wr = wv >> 1, wc = wv & 1;
  int lm = lane & 15, lk = lane >> 4;
  f32x4 acc[4][4];
#pragma unroll
  for (int mi = 0; mi < 4; mi++)
#pragma unroll
    for (int ni = 0; ni < 4; ni++) { acc[mi][ni][0]=0.f; acc[mi][ni][1]=0.f; acc[mi][ni][2]=0.f; acc[mi][ni][3]=0.f; }
  int ri = lane >> 2, ccx = lane & 3;
  int swze = (ccx ^ ((ri >> 1) & 3)) * 8;   // row-PAIR swizzle
  int g0 = wv * 2, g1 = g0 + 1;
  const unsigned short* pah0 = Ah + (size_t)(m0 + g0 * 16 + ri) * ldk + ko + swze;
  const unsigned short* pah1 = Ah + (size_t)(m0 + g1 * 16 + ri) * ldk + ko + swze;
  const unsigned short* pal0 = Al + (size_t)(m0 + g0 * 16 + ri) * ldk + ko + swze;
  const unsigned short* pal1 = Al + (size_t)(m0 + g1 * 16 + ri) * ldk + ko + swze;
  const unsigned short* pbh0 = Bh + (size_t)(n0 + g0 * 16 + ri) * ldk + ko + swze;
  const unsigned short* pbh1 = Bh + (size_t)(n0 + g1 * 16 + ri) * ldk + ko + swze;
  const unsigned short* pbl0 = Bl + (size_t)(n0 + g0 * 16 + ri) * ldk + ko + swze;
  const unsigned short* pbl1 = Bl + (size_t)(n0 + g1 * 16 + ri) * ldk + ko + swze;
  int d0 = g0 * 512, d1 = g1 * 512;
  auto stage = [&](int buf, int ks) {        // 8 gl_lds per wave
    gl_lds16(pah0 + ks, &sAh[buf][d0]); gl_lds16(pah1 + ks, &sAh[buf][d1]);
    gl_lds16(pal0 + ks, &sAl[buf][d0]); gl_lds16(pal1 + ks, &sAl[buf][d1]);
    gl_lds16(pbh0 + ks, &sBh[buf][d0]); gl_lds16(pbh1 + ks, &sBh[buf][d1]);
    gl_lds16(pbl0 + ks, &sBl[buf][d0]); gl_lds16(pbl1 + ks, &sBl[buf][d1]);
  };
  int nt = K2 / BKS;
  stage(0, 0);
  stage(1, BKS);
  int sa = (lk ^ ((lm >> 1) & 3)) * 8;      // read swizzle
  for (int t = 0; t < nt; t++) {
    if (t + 1 < nt) { asm volatile("s_waitcnt vmcnt(8)" ::: "memory"); }
    else            { asm volatile("s_waitcnt vmcnt(0)" ::: "memory"); }
    __builtin_amdgcn_sched_barrier(0);
    __builtin_amdgcn_s_barrier();
    int cur = t & 1;
    bf16x8 fah[4], fal[4], fbh[4], fbl[4];
#pragma unroll
    for (int mi = 0; mi < 4; mi++) {
      int ro = (wr * 64 + mi * 16 + lm) * 32 + sa;
      fah[mi] = ldbf8(&sAh[cur][ro]); fal[mi] = ldbf8(&sAl[cur][ro]);
    }
#pragma unroll
    for (int ni = 0; ni < 4; ni++) {
      int ro = (wc * 64 + ni * 16 + lm) * 32 + sa;
      fbh[ni] = ldbf8(&sBh[cur][ro]); fbl[ni] = ldbf8(&sBl[cur][ro]);
    }
#pragma unroll
    for (int mi = 0; mi < 4; mi++)
#pragma unroll
      for (int ni = 0; ni < 4; ni++) {
        acc[mi][ni] = mfma16(fah[mi], fbh[ni], acc[mi][ni]);
        acc[mi][ni] = mfma16(fal[mi], fbh[ni], acc[mi][ni]);
        acc[mi][ni] = mfma16(fah[mi], fbl[ni], acc[mi][ni]);
      }
    __builtin_amdgcn_s_barrier();
    if (t + 2 < nt) stage(cur, (t + 2) * BKS);
  }
  float* Cslab = Cp + (size_t)kh * M * N;
#pragma unroll
  for (int mi = 0; mi < 4; mi++)
#pragma unroll
    for (int ni = 0; ni < 4; ni++)
#pragma unroll
      for (int rr = 0; rr < 4; rr++) {
        int row = m0 + wr * 64 + mi * 16 + lk * 4 + rr;
        int col = n0 + wc * 64 + ni * 16 + lm;
        Cslab[(size_t)row * N + col] = acc[mi][ni][rr];
      }
}

// ---------------- Fused-transpose MoE GEMM: C[z] = A[z][M,K](bf16) * B[z][K,N](fp32)
// BK=64, 64KB LDS. A: gl_lds staging (0-conflict ^(row&7)). B: fp32 [K][N] read directly,
// converted via v_cvt_pk_bf16_f32, written as ONE b128 per (thread,i). SINGLE barrier/iter.
// Local optimum (R20 deeper-ILP and R22 smaller-BK both measured losses).
template<int GELU, int SPLITK>
__global__ __launch_bounds__(256) void gemm_moeF(
    const unsigned short* __restrict__ A, const float* __restrict__ Bsrc,
    void* __restrict__ Cp, int M, int N, int K, int ldA, int ldB) {
  __shared__ __align__(16) unsigned short sA[2][8192], sB[2][8192];
  int tid = threadIdx.x;
  int nbm = M >> 7, nbn = N >> 7, per = nbm * nbn;
  int cpx = gridDim.x >> 3;
  int bid = blockIdx.x;
  int l = (bid & 7) * cpx + (bid >> 3);
  int z = l / per;
  int r = l % per;
  int nb = r / nbm, mb = r % nbm;
  int m0 = mb * BM, n0 = nb * BM;
  const unsigned short* Az;
  const float* Bz;
  if (SPLITK) {
    int e = z >> 1, kh = z & 1;
    Az = A + (size_t)e * M * ldA + (size_t)kh * K;
    Bz = Bsrc + (size_t)e * (2 * (size_t)K) * ldB + (size_t)kh * K * ldB;
  } else {
    Az = A + (size_t)z * M * ldA;
    Bz = Bsrc + (size_t)z * (size_t)K * ldB;
  }
  int wv = tid >> 6, lane = tid & 63;
  int wr = wv >> 1, wc = wv & 1;
  int lm = lane & 15, lk = lane >> 4;
  f32x4 acc[4][4];
#pragma unroll
  for (int mi = 0; mi < 4; mi++)
#pragma unroll
    for (int ni = 0; ni < 4; ni++) { acc[mi][ni][0]=0.f; acc[mi][ni][1]=0.f; acc[mi][ni][2]=0.f; acc[mi][ni][3]=0.f; }
  // A staging: 16 groups of 8 rows; wave wv stages groups wv*4..wv*4+3 (4 gl_lds/wave)
  int ri = lane >> 3, cc8 = lane & 7;
  int swzeA = (cc8 ^ ri) * 8;
  const unsigned short* pa[4];
#pragma unroll
  for (int j = 0; j < 4; j++)
    pa[j] = Az + (size_t)(m0 + (wv * 4 + j) * 8 + ri) * ldA + swzeA;
  int dbaseA = wv * 4 * 512;
  auto stageA = [&](int buf, int ks) {
#pragma unroll
    for (int j = 0; j < 4; j++)
      gl_lds16(pa[j] + ks, &sA[buf][dbaseA + j * 512]);
  };
  // B staging: thread t covers k-pairs kpb..kpb+3 (one k-chunk), n = i*32 + tq (i=0..3)
  int tq = tid & 31;
  int kpb = (tid >> 5) * 4;
  int cpb = kpb >> 2;               // the single k-chunk this thread owns
  float bs[32];
  auto issueB = [&](int ks) {
#pragma unroll
    for (int j = 0; j < 4; j++) {
      int kk = (kpb + j) * 2;
#pragma unroll
      for (int rr = 0; rr < 2; rr++)
#pragma unroll
        for (int i = 0; i < 4; i++)
          bs[j * 8 + rr * 4 + i] = Bz[(size_t)(ks + kk + rr) * ldB + n0 + i * 32 + tq];
    }
  };
  auto cvtwriteB = [&](int buf) {
    unsigned short* dB = &sB[buf][0];
#pragma unroll
    for (int i = 0; i < 4; i++) {
      int n = i * 32 + tq;
      unsigned int p0 = cvt_pk_bf16(bs[0 * 8 + i], bs[0 * 8 + 4 + i]);
      unsigned int p1 = cvt_pk_bf16(bs[1 * 8 + i], bs[1 * 8 + 4 + i]);
      unsigned int p2 = cvt_pk_bf16(bs[2 * 8 + i], bs[2 * 8 + 4 + i]);
      unsigned int p3 = cvt_pk_bf16(bs[3 * 8 + i], bs[3 * 8 + 4 + i]);
      uint4 w; w.x = p0; w.y = p1; w.z = p2; w.w = p3;
      *(uint4*)&dB[n * 64 + ((cpb ^ (n & 7)) * 8)] = w;   // one b128 write
    }
  };
  int nt = K / BKM;
  // prologue: tile 0
  stageA(0, 0);
  issueB(0);
  asm volatile("s_waitcnt vmcnt(0)" ::: "memory");
  __builtin_amdgcn_sched_barrier(0);
  cvtwriteB(0);
  __syncthreads();
  int sw = lm & 7;
  for (int t = 0; t < nt; t++) {
    int cur = t & 1;
    bool more = (t + 1 < nt);
    if (more) {
      stageA(cur ^ 1, (t + 1) * BKM);     // writes buf[cur^1]: readers done at iter t-1
      issueB((t + 1) * BKM);
      __builtin_amdgcn_sched_barrier(0);  // pin load issue before compute
    }
#pragma unroll
    for (int h = 0; h < 2; h++) {
      int kc = lk + h * 4;
      int sa = (kc ^ sw) * 8;
      bf16x8 fa[4], fb[4];
#pragma unroll
      for (int mi = 0; mi < 4; mi++) fa[mi] = ldbf8(&sA[cur][(wr * 64 + mi * 16 + lm) * 64 + sa]);
#pragma unroll
      for (int ni = 0; ni < 4; ni++) fb[ni] = ldbf8(&sB[cur][(wc * 64 + ni * 16 + lm) * 64 + sa]);
#pragma unroll
      for (int mi = 0; mi < 4; mi++)
#pragma unroll
        for (int ni = 0; ni < 4; ni++)
          acc[mi][ni] = mfma16(fa[mi], fb[ni], acc[mi][ni]);
    }
    if (more) {
      asm volatile("s_waitcnt vmcnt(0)" ::: "memory");   // A(t+1) landed in LDS, B(t+1) in regs
      __builtin_amdgcn_sched_barrier(0);
      cvtwriteB(cur ^ 1);                 // writes buf[cur^1]: no reader this iter
      __syncthreads();                    // single barrier: publish A+B(t+1); order next iter's writes
    }
  }
#pragma unroll
  for (int mi = 0; mi < 4; mi++)
#pragma unroll
    for (int ni = 0; ni < 4; ni++)
#pragma unroll
      for (int rr = 0; rr < 4; rr++) {
        int row = m0 + wr * 64 + mi * 16 + lk * 4 + rr;
        int col = n0 + wc * 64 + ni * 16 + lm;
        size_t idx = (size_t)z * M * N + (size_t)row * N + col;
        float v = acc[mi][ni][rr];
        if (GELU) {
          float gv = 0.5f * v * (1.0f + erff(v * 0.70710678118654752f));
          ((unsigned short*)Cp)[idx] = f2bf(gv);
        } else {
          ((float*)Cp)[idx] = v;
        }
      }
}

// ---------------- repack qkv partial slabs (sum) -> Q/K (bf16 hi/lo) and V^T (bf16 hi/lo)
__global__ __launch_bounds__(256) void repack_kernel(
    const float* __restrict__ qkvp,
    unsigned short* __restrict__ Qh, unsigned short* __restrict__ Ql,
    unsigned short* __restrict__ Kh, unsigned short* __restrict__ Kl,
    unsigned short* __restrict__ Vh, unsigned short* __restrict__ Vl) {
  int t = blockIdx.x; int s = t / BATCH, b = t % BATCH;
  const float* row0 = qkvp + (size_t)t * QKVSZ;
  const float* row1 = row0 + (size_t)TTOK * QKVSZ;
  int tid = threadIdx.x;
  for (int idx = tid; idx < 2048; idx += 256) {
    int hh = idx >> 7, d = idx & 127;
    int o_in = (hh >> 2) * GRP + (hh & 3) * 128 + d;
    float val = row0[o_in] + row1[o_in];
    unsigned short hv = f2bf(val), lv = f2bf(val - bf2f(hv));
    size_t o = ((size_t)(b * NHEAD + hh) * S_LEN + s) * HDIM + d;
    Qh[o] = hv; Ql[o] = lv;
  }
  for (int idx = tid; idx < 512; idx += 256) {
    int g = idx >> 7, d = idx & 127;
    int o_in = g * GRP + 512 + d;
    float val = row0[o_in] + row1[o_in];
    unsigned short hv = f2bf(val), lv = f2bf(val - bf2f(hv));
    size_t o = ((size_t)(b * KVHN + g) * S_LEN + s) * HDIM + d;
    Kh[o] = hv; Kl[o] = lv;
  }
  for (int idx = tid; idx < 512; idx += 256) {
    int g = idx >> 7, d = idx & 127;
    int o_in = g * GRP + 640 + d;
    float val = row0[o_in] + row1[o_in];
    unsigned short hv = f2bf(val), lv = f2bf(val - bf2f(hv));
    size_t o = ((size_t)(b * KVHN + g) * HDIM + d) * S_LEN + s;
    Vh[o] = hv; Vl[o] = lv;
  }
}

// ---------------- causal flash attention: 1 block = 4 waves = 4 heads of one KV group,
// 16-query tile; K chunk (hi+lo) staged in LDS via gl_lds dbuf with XOR-swizzled source.
__global__ __launch_bounds__(256) void attn4(
    const unsigned short* __restrict__ Qh, const unsigned short* __restrict__ Ql,
    const unsigned short* __restrict__ Kh, const unsigned short* __restrict__ Kl,
    const unsigned short* __restrict__ Vh, const unsigned short* __restrict__ Vl,
    unsigned short* __restrict__ Oh, unsigned short* __restrict__ Ol) {
  __shared__ __align__(16) unsigned short sK[2][2][32 * 128];       // [buf][hi/lo][key][d^swz]
  __shared__ __align__(16) unsigned short Ph[4][2][16 * LDT], Pl[4][2][16 * LDT];
  int qt = blockIdx.x, g = blockIdx.y, b = blockIdx.z;
  int tid = threadIdx.x, wv = tid >> 6, lane = tid & 63;
  int lm = lane & 15, lk = lane >> 4;
  int hh = g * 4 + wv;
  int q0 = qt * 16;
  const float scale = 0.08838834764831845f;  // 1/sqrt(128)
  int r0 = wv * 4 + (lane >> 4);
  int c16 = lane & 15;
  int dsw = (c16 * 8) ^ ((r0 & 7) << 3);
  const unsigned short* kbh = Kh + (size_t)((b * KVHN + g) * S_LEN) * HDIM;
  const unsigned short* kbl = Kl + (size_t)((b * KVHN + g) * S_LEN) * HDIM;
  auto stageK = [&](int buf, int k0) {
    unsigned short* dh = &sK[buf][0][0];
    unsigned short* dl = &sK[buf][1][0];
    gl_lds16(kbh + (size_t)(k0 + r0) * HDIM + dsw,      dh + wv * 512);
    gl_lds16(kbh + (size_t)(k0 + r0 + 16) * HDIM + dsw, dh + 2048 + wv * 512);
    gl_lds16(kbl + (size_t)(k0 + r0) * HDIM + dsw,      dl + wv * 512);
    gl_lds16(kbl + (size_t)(k0 + r0 + 16) * HDIM + dsw, dl + 2048 + wv * 512);
  };
  bf16x8 qfh[4], qfl[4];
  {
    size_t qb = ((size_t)(b * NHEAD + hh) * S_LEN + q0 + lm) * HDIM + lk * 8;
#pragma unroll
    for (int dc = 0; dc < 4; dc++) {
      qfh[dc] = ldbf8(Qh + qb + dc * 32);
      qfl[dc] = ldbf8(Ql + qb + dc * 32);
    }
  }
  f32x4 accO[8];
#pragma unroll
  for (int dt = 0; dt < 8; dt++) { accO[dt][0]=0.f; accO[dt][1]=0.f; accO[dt][2]=0.f; accO[dt][3]=0.f; }
  float mrun = -3.4e38f, lrun = 0.f;
  int nch = (q0 + 47) >> 5;
  stageK(0, 0);
  asm volatile("s_waitcnt vmcnt(0)" ::: "memory");
  __syncthreads();
  int cur = 0;
  for (int ck = 0; ck < nch; ck++) {
    int k0 = ck * 32;
    if (ck + 1 < nch) stageK(cur ^ 1, k0 + 32);
    f32x4 sc[2];
    sc[0][0]=0.f; sc[0][1]=0.f; sc[0][2]=0.f; sc[0][3]=0.f;
    sc[1][0]=0.f; sc[1][1]=0.f; sc[1][2]=0.f; sc[1][3]=0.f;
#pragma unroll
    for (int t2 = 0; t2 < 2; t2++) {
      int row = t2 * 16 + lm;
#pragma unroll
      for (int dc = 0; dc < 4; dc++) {
        int ce = (dc * 32 + lk * 8) ^ ((row & 7) << 3);
        bf16x8 kfh = ldbf8(&sK[cur][0][row * 128 + ce]);
        bf16x8 kfl = ldbf8(&sK[cur][1][row * 128 + ce]);
        sc[t2] = mfma16(kfh, qfh[dc], sc[t2]);
        sc[t2] = mfma16(kfl, qfh[dc], sc[t2]);
        sc[t2] = mfma16(kfh, qfl[dc], sc[t2]);
      }
    }
    float pv[8];
    float pmax = -3.4e38f;
#pragma unroll
    for (int t2 = 0; t2 < 2; t2++)
#pragma unroll
      for (int rr = 0; rr < 4; rr++) {
        int key = k0 + t2 * 16 + lk * 4 + rr;
        float sv = sc[t2][rr] * scale;
        if (key > q0 + lm) sv = -3.4e38f;
        pv[t2 * 4 + rr] = sv;
        pmax = fmaxf(pmax, sv);
      }
    pmax = fmaxf(pmax, __shfl_xor(pmax, 16));
    pmax = fmaxf(pmax, __shfl_xor(pmax, 32));
    float mnew = fmaxf(mrun, pmax);
    float fsc = expf(mrun - mnew);
    float psum = 0.f;
#pragma unroll
    for (int j = 0; j < 8; j++) { pv[j] = expf(pv[j] - mnew); psum += pv[j]; }
    psum = psum + __shfl_xor(psum, 16);
    psum = psum + __shfl_xor(psum, 32);
    lrun = lrun * fsc + psum;
#pragma unroll
    for (int dt = 0; dt < 8; dt++)
#pragma unroll
      for (int rr = 0; rr < 4; rr++) accO[dt][rr] *= fsc;
    int pb = ck & 1;
#pragma unroll
    for (int t2 = 0; t2 < 2; t2++) {
      u16x4 wh, wl;
#pragma unroll
      for (int rr = 0; rr < 4; rr++) {
        float p = pv[t2 * 4 + rr];
        unsigned short hv = f2bf(p);
        wh[rr] = hv; wl[rr] = f2bf(p - bf2f(hv));
      }
      int ad = lm * LDT + t2 * 16 + lk * 4;
      *(u16x4*)&Ph[wv][pb][ad] = wh;
      *(u16x4*)&Pl[wv][pb][ad] = wl;
    }
    bf16x8 pfh = ldbf8(&Ph[wv][pb][lm * LDT + lk * 8]);
    bf16x8 pfl = ldbf8(&Pl[wv][pb][lm * LDT + lk * 8]);
#pragma unroll
    for (int dt = 0; dt < 8; dt++) {
      size_t vo = ((size_t)((b * KVHN + g) * HDIM + dt * 16 + lm)) * S_LEN + k0 + lk * 8;
      bf16x8 vfh = ldbf8(Vh + vo);
      bf16x8 vfl = ldbf8(Vl + vo);
      accO[dt] = mfma16(vfh, pfh, accO[dt]);
      accO[dt] = mfma16(vfl, pfh, accO[dt]);
      accO[dt] = mfma16(vfh, pfl, accO[dt]);
    }
    mrun = mnew;
    asm volatile("s_waitcnt vmcnt(0)" ::: "memory");
    __syncthreads();
    cur ^= 1;
  }
  float inv = 1.0f / lrun;
#pragma unroll
  for (int dt = 0; dt < 8; dt++)
#pragma unroll
    for (int rr = 0; rr < 4; rr++) {
      float o = accO[dt][rr] * inv;
      int d = dt * 16 + lk * 4 + rr;
      int srow = q0 + lm;
      size_t idx = ((size_t)(srow * BATCH + b)) * HIDN + hh * HDIM + d;
      unsigned short hv = f2bf(o);
      Oh[idx] = hv; Ol[idx] = f2bf(o - bf2f(hv));
    }
}

// ---------------- routing: softmax, top-2 (first-max semantics), capacity cumsum, scatter
__global__ __launch_bounds__(1024) void routing_kernel(
    const float* __restrict__ L, int* __restrict__ slot_token,
    int* __restrict__ tE1, int* __restrict__ tP1, float* __restrict__ tG1,
    int* __restrict__ tE2, int* __restrict__ tP2, float* __restrict__ tG2) {
  __shared__ unsigned int sc[1024][8];
  __shared__ unsigned int stot[8];
  int i = threadIdx.x;
  for (int j = i; j < NEXP * CAPC; j += 1024) slot_token[j] = -1;

  int e1[2], e2[2]; float g1[2], g2[2];
  unsigned int v[8] = {0,0,0,0,0,0,0,0};
#pragma unroll
  for (int u = 0; u < 2; u++) {
    int t = 2 * i + u;
    float l[8];
    float m = -3.4e38f;
#pragma unroll
    for (int e = 0; e < 8; e++) { l[e] = L[(size_t)t * NEXP + e]; m = fmaxf(m, l[e]); }
    float ex[8]; float se = 0.f;
#pragma unroll
    for (int e = 0; e < 8; e++) { ex[e] = expf(l[e] - m); se += ex[e]; }
    int b1 = 0; float bv = l[0];
    for (int e = 1; e < 8; e++) if (l[e] > bv) { bv = l[e]; b1 = e; }
    int b2 = -1; float bv2 = 0.f;
    for (int e = 0; e < 8; e++) {
      if (e == b1) continue;
      if (b2 < 0 || l[e] > bv2) { b2 = e; bv2 = l[e]; }
    }
    e1[u] = b1; e2[u] = b2;
    g1[u] = ex[b1] / se; g2[u] = ex[b2] / se;
    v[b1 >> 1] += 1u << ((b1 & 1) * 16);
    v[4 + (b2 >> 1)] += 1u << ((b2 & 1) * 16);
  }
  unsigned int cur[8];
#pragma unroll
  for (int k = 0; k < 8; k++) cur[k] = v[k];
  for (int off = 1; off < 1024; off <<= 1) {
#pragma unroll
    for (int k = 0; k < 8; k++) sc[i][k] = cur[k];
    __syncthreads();
    if (i >= off) {
#pragma unroll
      for (int k = 0; k < 8; k++) cur[k] += sc[i - off][k];
    }
    __syncthreads();
  }
  if (i == 1023) {
#pragma unroll
    for (int k = 0; k < 8; k++) stot[k] = cur[k];
  }
  __syncthreads();
  unsigned int excl[8];
#pragma unroll
  for (int k = 0; k < 8; k++) excl[k] = cur[k] - v[k];

#pragma unroll
  for (int u = 0; u < 2; u++) {
    int t = 2 * i + u;
    int a1 = e1[u], a2 = e2[u];
    int loc1 = (int)((excl[a1 >> 1] >> ((a1 & 1) * 16)) & 0xFFFFu);
    int loc2 = (int)((excl[4 + (a2 >> 1)] >> ((a2 & 1) * 16)) & 0xFFFFu);
    if (u == 1) {
      if (a1 == e1[0]) loc1 += 1;
      if (a2 == e2[0]) loc2 += 1;
    }
    loc2 += (int)((stot[a2 >> 1] >> ((a2 & 1) * 16)) & 0xFFFFu);  // + total first-choice count
    bool k1 = loc1 < CAPC, k2 = loc2 < CAPC;
    float G1 = k1 ? g1[u] : 0.f, G2 = k2 ? g2[u] : 0.f;
    float den = fmaxf(G1 + G2, 1.1920929e-07f);
    G1 /= den; G2 /= den;
    tE1[t] = a1; tP1[t] = k1 ? loc1 : 0; tG1[t] = G1;
    tE2[t] = a2; tP2[t] = k2 ? loc2 : 0; tG2[t] = G2;
    if (k1) slot_token[a1 * CAPC + loc1] = t;
    if (k2) slot_token[a2 * CAPC + loc2] = t;
  }
}

// ---------------- gather tokens into expert capacity slots (bf16)
__global__ __launch_bounds__(256) void gather_kernel(
    const int* __restrict__ slot_token, const unsigned short* __restrict__ Xb,
    unsigned short* __restrict__ XE) {
  int slot = blockIdx.x;
  int t = slot_token[slot];
  unsigned short* dst = XE + (size_t)slot * HIDN + threadIdx.x * 8;
  if (t >= 0) {
    *(u16x8*)dst = *(const u16x8*)(Xb + (size_t)t * HIDN + threadIdx.x * 8);
  } else {
    u16x8 zz = {0,0,0,0,0,0,0,0};
    *(u16x8*)dst = zz;
  }
}

// ---------------- combine: out = h1 + g1*(eoA+eoB)[e1,p1] + g2*(eoA+eoB)[e2,p2]
// eo2 layout: [e*2 + kh][CAPC][HIDN] fp32 partials (split-K halves)
__global__ __launch_bounds__(256) void combine_kernel(
    const float* __restrict__ h1, const float* __restrict__ eo2,
    const int* __restrict__ tE1, const int* __restrict__ tP1, const float* __restrict__ tG1,
    const int* __restrict__ tE2, const int* __restrict__ tP2, const float* __restrict__ tG2,
    float* __restrict__ outp) {
  int t = blockIdx.x, tid = threadIdx.x;
  float G1 = tG1[t], G2 = tG2[t];
  size_t MN = (size_t)CAPC * HIDN;
  size_t b1 = ((size_t)tE1[t] * 2) * MN + (size_t)tP1[t] * HIDN;
  size_t b2 = ((size_t)tE2[t] * 2) * MN + (size_t)tP2[t] * HIDN;
  size_t rowo = (size_t)t * HIDN;
  int c = tid * 8;
#pragma unroll
  for (int j = 0; j < 8; j += 4) {
    float4 hv  = *(const float4*)(h1 + rowo + c + j);
    float4 e1a = *(const float4*)(eo2 + b1 + c + j);
    float4 e1b = *(const float4*)(eo2 + b1 + MN + c + j);
    float4 e2a = *(const float4*)(eo2 + b2 + c + j);
    float4 e2b = *(const float4*)(eo2 + b2 + MN + c + j);
    float4 o;
    o.x = hv.x + G1 * (e1a.x + e1b.x) + G2 * (e2a.x + e2b.x);
    o.y = hv.y + G1 * (e1a.y + e1b.y) + G2 * (e2a.y + e2b.y);
    o.z = hv.z + G1 * (e1a.z + e1b.z) + G2 * (e2a.z + e2b.z);
    o.w = hv.w + G1 * (e1a.w + e1b.w) + G2 * (e2a.w + e2b.w);
    *(float4*)(outp + rowo + c + j) = o;
  }
}

extern "C" void kernel_launch(void* const* d_in, const int* in_sizes, int n_in,
                              void* d_out, int out_size, void* d_ws, size_t ws_size,
                              hipStream_t stream) {
  const float* hs    = (const float*)d_in[0];
  const float* ln1w  = (const float*)d_in[1];
  const float* ln1b  = (const float*)d_in[2];
  const float* qkvw  = (const float*)d_in[3];
  const float* projw = (const float*)d_in[4];
  const float* ln2w  = (const float*)d_in[5];
  const float* ln2b  = (const float*)d_in[6];
  const float* gatew = (const float*)d_in[7];
  const float* w1    = (const float*)d_in[8];
  const float* w2    = (const float*)d_in[9];
  float* outp = (float*)d_out;

  char* base = (char*)d_ws;
  size_t off = 0;
  auto alloc = [&](size_t bytes) -> void* {
    void* r = base + off;
    off = (off + bytes + 255) & ~(size_t)255;
    return r;
  };
  unsigned short* ln1h = (unsigned short*)alloc((size_t)TTOK * HIDN * 2);
  unsigned short* ln1l = (unsigned short*)alloc((size_t)TTOK * HIDN * 2);
  float* qkvp = (float*)alloc((size_t)2 * TTOK * QKVSZ * 4);          // split-K partial slabs
  unsigned short* Qh = (unsigned short*)alloc((size_t)BATCH * NHEAD * S_LEN * HDIM * 2);
  unsigned short* Ql = (unsigned short*)alloc((size_t)BATCH * NHEAD * S_LEN * HDIM * 2);
  unsigned short* Kh = (unsigned short*)alloc((size_t)BATCH * KVHN * S_LEN * HDIM * 2);
  unsigned short* Kl = (unsigned short*)alloc((size_t)BATCH * KVHN * S_LEN * HDIM * 2);
  unsigned short* Vh = (unsigned short*)alloc((size_t)BATCH * KVHN * S_LEN * HDIM * 2);
  unsigned short* Vl = (unsigned short*)alloc((size_t)BATCH * KVHN * S_LEN * HDIM * 2);
  unsigned short* oh = (unsigned short*)alloc((size_t)TTOK * HIDN * 2);
  unsigned short* ol = (unsigned short*)alloc((size_t)TTOK * HIDN * 2);
  float* h1p = (float*)alloc((size_t)2 * TTOK * HIDN * 4);            // proj partial slabs
  float* h1 = (float*)alloc((size_t)TTOK * HIDN * 4);
  unsigned short* xb = (unsigned short*)alloc((size_t)TTOK * HIDN * 2);
  float* logits = (float*)alloc((size_t)TTOK * NEXP * 4);
  int* slot = (int*)alloc((size_t)NEXP * CAPC * 4);
  int* tE1 = (int*)alloc((size_t)TTOK * 4);
  int* tP1 = (int*)alloc((size_t)TTOK * 4);
  int* tE2 = (int*)alloc((size_t)TTOK * 4);
  int* tP2 = (int*)alloc((size_t)TTOK * 4);
  float* tG1 = (float*)alloc((size_t)TTOK * 4);
  float* tG2 = (float*)alloc((size_t)TTOK * 4);
  unsigned short* xe = (unsigned short*)alloc((size_t)NEXP * CAPC * HIDN * 2);
  unsigned short* hmid = (unsigned short*)alloc((size_t)NEXP * CAPC * FFND * 2);
  float* eo2 = (float*)alloc((size_t)NEXP * 2 * CAPC * HIDN * 4);     // moe<0> split-K partials
  unsigned short* qwh = (unsigned short*)alloc((size_t)QKVSZ * HIDN * 2);
  unsigned short* qwl = (unsigned short*)alloc((size_t)QKVSZ * HIDN * 2);
  unsigned short* pwh = (unsigned short*)alloc((size_t)HIDN * HIDN * 2);
  unsigned short* pwl = (unsigned short*)alloc((size_t)HIDN * HIDN * 2);
  (void)ws_size; (void)in_sizes; (void)n_in; (void)out_size;

  // attention path
  ln_kernel<<<TTOK, 256, 0, stream>>>(hs, ln1w, ln1b, ln1h, ln1l, nullptr);
  wsplit<<<(QKVSZ * HIDN) / 2048, 256, 0, stream>>>(qkvw, qwh, qwl);
  wsplit<<<(HIDN * HIDN) / 2048, 256, 0, stream>>>(projw, pwh, pwl);
  // qkv: split-K x2 -> 768 blocks (3/CU)
  gemm_x3s<<<dim3((QKVSZ / BM) * (TTOK / BM) * 2), 256, 0, stream>>>(
      ln1h, ln1l, qwh, qwl, qkvp, TTOK, QKVSZ, HIDN / 2, HIDN);
  repack_kernel<<<TTOK, 256, 0, stream>>>(qkvp, Qh, Ql, Kh, Kl, Vh, Vl);
  attn4<<<dim3(S_LEN / 16, KVHN, BATCH), 256, 0, stream>>>(Qh, Ql, Kh, Kl, Vh, Vl, oh, ol);
  // proj: split-K x2 -> 512 blocks (2/CU)
  gemm_x3s<<<dim3((HIDN / BM) * (TTOK / BM) * 2), 256, 0, stream>>>(
      oh, ol, pwh, pwl, h1p, TTOK, HIDN, HIDN / 2, HIDN);
  // fused MoE front: h1 = hs + partials; LN2; xb; gate logits
  moe_front<<<TTOK, 256, 0, stream>>>(hs, h1p, ln2w, ln2b, gatew, h1, xb, logits);
  routing_kernel<<<1, 1024, 0, stream>>>(logits, slot, tE1, tP1, tG1, tE2, tP2, tG2);
  gather_kernel<<<NEXP * CAPC, 256, 0, stream>>>(slot, xb, xe);
  // moe<1>: fused-transpose, B = w1 fp32 [E][HIDN][FFND] read directly
  gemm_moeF<1, 0><<<dim3((FFND / BM) * (CAPC / BM) * NEXP), 256, 0, stream>>>(
      xe, w1, (void*)hmid, CAPC, FFND, HIDN, HIDN, FFND);
  // moe<0>: fused-transpose + split-K x2, B = w2 fp32 [E][FFND][HIDN]
  gemm_moeF<0, 1><<<dim3((HIDN / BM) * (CAPC / BM) * NEXP * 2), 256, 0, stream>>>(
      hmid, w2, (void*)eo2, CAPC, HIDN, FFND / 2, FFND, HIDN);
  combine_kernel<<<TTOK, 256, 0, stream>>>(h1, eo2, tE1, tP1, tG1, tE2, tP2, tG2, outp);
}